// Round 3
// baseline (259.196 us; speedup 1.0000x reference)
//
#include <hip/hip_runtime.h>
#include <hip/hip_bf16.h>

typedef __bf16 bf16;
typedef __bf16 bf16x8 __attribute__((ext_vector_type(8)));
typedef float f32x4 __attribute__((ext_vector_type(4)));

#define MFMA16(a, b, c) __builtin_amdgcn_mfma_f32_16x16x32_bf16((a), (b), (c), 0, 0, 0)

// Problem: B=2, L=4096, D=1024, H=8, Hd=128, CHUNK=64, NCHUNK=64
// gamma_h = 1 - 2^(-5-h).  Inputs fp32, OUTPUT fp32 (reference dtype).

// ---------------------------------------------------------------------------
// Kernel 0: transpose + fp32->bf16 the four 1024x1024 weights.
// Wt[w][n][k] = (bf16)W[k][n]
// ---------------------------------------------------------------------------
__global__ __launch_bounds__(256) void transpose_w(
    const float* __restrict__ Wq, const float* __restrict__ Wk,
    const float* __restrict__ Wv, const float* __restrict__ Wo,
    bf16* __restrict__ Wt) {
  __shared__ bf16 t[64 * 72];
  const float* src = (blockIdx.z == 0) ? Wq : (blockIdx.z == 1) ? Wk
                     : (blockIdx.z == 2) ? Wv : Wo;
  bf16* dst = Wt + (size_t)blockIdx.z * 1024 * 1024;
  const int k0 = blockIdx.x * 64, n0 = blockIdx.y * 64;
  const int tid = threadIdx.x;
#pragma unroll
  for (int s = 0; s < 4; ++s) {
    int u = tid + s * 256;          // 0..1023
    int r = u >> 4, c4 = (u & 15) * 4;
    float4 f = *(const float4*)&src[(size_t)(k0 + r) * 1024 + n0 + c4];
    t[r * 72 + c4 + 0] = (bf16)f.x;
    t[r * 72 + c4 + 1] = (bf16)f.y;
    t[r * 72 + c4 + 2] = (bf16)f.z;
    t[r * 72 + c4 + 3] = (bf16)f.w;
  }
  __syncthreads();
#pragma unroll
  for (int s = 0; s < 2; ++s) {
    int u = tid + s * 256;
    int r = u >> 3, cc = u & 7;     // output row n0+r, k-chunk cc
    union { bf16 h[8]; uint4 u4; } pk;
#pragma unroll
    for (int j = 0; j < 8; ++j) pk.h[j] = t[(cc * 8 + j) * 72 + r];
    *(uint4*)&dst[(size_t)(n0 + r) * 1024 + k0 + cc * 8] = pk.u4;
  }
}

// ---------------------------------------------------------------------------
// Kernel 1: C = alpha * (A @ Bt^T).  A: M x 1024 row-major (fp32 OR bf16),
// Bt: 1024 x 1024 = B^T row-major bf16, C: M x 1024 (bf16 OR fp32 per TC).
// 128x128 tile, BK=64, 4 waves, 16x16x32 bf16 MFMA.
// ---------------------------------------------------------------------------
template <typename TA, typename TC>
__global__ __launch_bounds__(256) void gemm_bt(
    const TA* __restrict__ A, const bf16* __restrict__ Bt,
    TC* __restrict__ C, float alpha) {
  __shared__ bf16 lA[128 * 72];
  __shared__ bf16 lB[128 * 72];
  const int m0 = blockIdx.x * 128, n0 = blockIdx.y * 128;
  const int tid = threadIdx.x;
  const int w = tid >> 6, lane = tid & 63, lr = lane & 15, quad = lane >> 4;
  const int wm = w >> 1, wn = w & 1;
  f32x4 acc[4][4] = {};

  for (int it = 0; it < 16; ++it) {
    const int k0 = it * 64;
    // stage A (convert if fp32)
    if constexpr (sizeof(TA) == 4) {
#pragma unroll
      for (int s = 0; s < 8; ++s) {
        int u = tid + s * 256;          // 0..2047 -> 128 rows x 16 float4
        int r = u >> 4, c4 = (u & 15) * 4;
        float4 f = *(const float4*)&A[(size_t)(m0 + r) * 1024 + k0 + c4];
        lA[r * 72 + c4 + 0] = (bf16)f.x;
        lA[r * 72 + c4 + 1] = (bf16)f.y;
        lA[r * 72 + c4 + 2] = (bf16)f.z;
        lA[r * 72 + c4 + 3] = (bf16)f.w;
      }
    } else {
#pragma unroll
      for (int s = 0; s < 4; ++s) {
        int u = tid + s * 256;
        int r = u >> 3, cc = u & 7;
        *(uint4*)&lA[r * 72 + cc * 8] =
            *(const uint4*)&A[(size_t)(m0 + r) * 1024 + k0 + cc * 8];
      }
    }
    // stage B (always bf16)
#pragma unroll
    for (int s = 0; s < 4; ++s) {
      int u = tid + s * 256;
      int r = u >> 3, cc = u & 7;
      *(uint4*)&lB[r * 72 + cc * 8] =
          *(const uint4*)&Bt[(size_t)(n0 + r) * 1024 + k0 + cc * 8];
    }
    __syncthreads();
#pragma unroll
    for (int kk = 0; kk < 2; ++kk) {
      bf16x8 af[4], bfv[4];
#pragma unroll
      for (int i = 0; i < 4; ++i)
        af[i] = *(bf16x8*)&lA[(wm * 64 + i * 16 + lr) * 72 + kk * 32 + quad * 8];
#pragma unroll
      for (int j = 0; j < 4; ++j)
        bfv[j] = *(bf16x8*)&lB[(wn * 64 + j * 16 + lr) * 72 + kk * 32 + quad * 8];
#pragma unroll
      for (int i = 0; i < 4; ++i)
#pragma unroll
        for (int j = 0; j < 4; ++j)
          acc[i][j] = MFMA16(af[i], bfv[j], acc[i][j]);
    }
    __syncthreads();
  }
  // Epilogue: D layout col=lane&15, row=quad*4+r
#pragma unroll
  for (int i = 0; i < 4; ++i) {
#pragma unroll
    for (int j = 0; j < 4; ++j) {
      const int row = m0 + wm * 64 + i * 16 + quad * 4;
      const int col = n0 + wn * 64 + j * 16 + lr;
#pragma unroll
      for (int r = 0; r < 4; ++r)
        C[(size_t)(row + r) * 1024 + col] = (TC)(acc[i][j][r] * alpha);
    }
  }
}

// ---------------------------------------------------------------------------
// Kernel 2 (phase A): per-(b,h,chunk) T^T[dv][dk] = sum_c k[c][dk]*g^(63-c)*v[c][dv]
// grid = 1024 (bh*64+n), bf16 output at Tb + g*16384, layout [dv][dk].
// ---------------------------------------------------------------------------
__global__ __launch_bounds__(256) void chunk_kv(
    const bf16* __restrict__ kb, const bf16* __restrict__ vb,
    bf16* __restrict__ Tb) {
  __shared__ bf16 lK[128 * 72];  // [dk][c] with decay folded in
  __shared__ bf16 lV[128 * 72];  // [dv][c]
  const int g = blockIdx.x;
  const int bh = g >> 6, n = g & 63, b = bh >> 3, h = bh & 7;
  const float log2g = log2f(1.0f - exp2f(-5.0f - (float)h));
  const int tid = threadIdx.x;
  const size_t rowbase = (size_t)(b * 4096 + n * 64) * 1024 + h * 128;
  const bf16* kc = kb + rowbase;
  const bf16* vc = vb + rowbase;
#pragma unroll
  for (int s = 0; s < 4; ++s) {
    int u = tid + s * 256;
    int c = u >> 4, d0 = (u & 15) * 8;
    union { uint4 u4; bf16 h8[8]; } kv, vv;
    kv.u4 = *(const uint4*)&kc[(size_t)c * 1024 + d0];
    vv.u4 = *(const uint4*)&vc[(size_t)c * 1024 + d0];
    const float dec = exp2f((float)(63 - c) * log2g);
#pragma unroll
    for (int j = 0; j < 8; ++j) {
      lK[(d0 + j) * 72 + c] = (bf16)((float)kv.h8[j] * dec);
      lV[(d0 + j) * 72 + c] = vv.h8[j];
    }
  }
  __syncthreads();
  const int w = tid >> 6, lane = tid & 63, lr = lane & 15, quad = lane >> 4;
  const int wm = w >> 1, wn = w & 1;
  f32x4 acc[4][4] = {};
#pragma unroll
  for (int kk = 0; kk < 2; ++kk) {
    bf16x8 af[4], bv[4];
#pragma unroll
    for (int i = 0; i < 4; ++i)
      af[i] = *(bf16x8*)&lK[(wm * 64 + i * 16 + lr) * 72 + kk * 32 + quad * 8];
#pragma unroll
    for (int j = 0; j < 4; ++j)
      bv[j] = *(bf16x8*)&lV[(wn * 64 + j * 16 + lr) * 72 + kk * 32 + quad * 8];
#pragma unroll
    for (int i = 0; i < 4; ++i)
#pragma unroll
      for (int j = 0; j < 4; ++j)
        acc[i][j] = MFMA16(af[i], bv[j], acc[i][j]);
  }
  bf16* tchunk = Tb + (size_t)g * 16384;
#pragma unroll
  for (int i = 0; i < 4; ++i) {
#pragma unroll
    for (int j = 0; j < 4; ++j) {
      const int dk = wm * 64 + i * 16 + quad * 4;  // row of T (r advances dk)
      const int dv = wn * 64 + j * 16 + lr;        // col of T
      union { bf16 h4[4]; uint2 u2; } pk;
#pragma unroll
      for (int r = 0; r < 4; ++r) pk.h4[r] = (bf16)acc[i][j][r];
      *(uint2*)&tchunk[(size_t)dv * 128 + dk] = pk.u2;  // transposed store
    }
  }
}

// ---------------------------------------------------------------------------
// Kernel 3 (phase B): in-place exclusive prefix scan over chunks:
// slot n <- S_{n-1};  S <- gamma^64 * S + T_n.  fp32 accumulator in register.
// grid = 1024 (bh*64 + seg), each thread owns one state element.
// ---------------------------------------------------------------------------
__global__ __launch_bounds__(256) void scan_state(bf16* __restrict__ Tb) {
  const int blk = blockIdx.x;
  const int bh = blk >> 6, seg = blk & 63, h = bh & 7;
  const float gs = exp2f(64.0f * log2f(1.0f - exp2f(-5.0f - (float)h)));
  const size_t base = (size_t)bh * 64 * 16384 + (size_t)seg * 256 + threadIdx.x;
  float S = 0.0f;
#pragma unroll 8
  for (int n = 0; n < 64; ++n) {
    const size_t a = base + (size_t)n * 16384;
    const float t = (float)Tb[a];
    Tb[a] = (bf16)S;
    S = gs * S + t;
  }
}

// ---------------------------------------------------------------------------
// Kernel 4 (phase C): per-(b,h,chunk) output:
// P = (q@k^T) * D(mask/decay);  o = P@v + (q * g^(i+1)) @ S_prev
// ---------------------------------------------------------------------------
__global__ __launch_bounds__(256) void chunk_out(
    const bf16* __restrict__ qb, const bf16* __restrict__ kb,
    const bf16* __restrict__ vb, const bf16* __restrict__ Sp,
    bf16* __restrict__ ob) {
  __shared__ bf16 lQ[64 * 136];   // [c][dk]
  __shared__ bf16 lK[64 * 136];   // [c][dk]
  __shared__ bf16 lVt[128 * 72];  // [dv][c]
  __shared__ bf16 lP[64 * 72];    // [ci][cj] masked scores
  const int g = blockIdx.x;
  const int bh = g >> 6, n = g & 63, b = bh >> 3, h = bh & 7;
  const float log2g = log2f(1.0f - exp2f(-5.0f - (float)h));
  const int tid = threadIdx.x;
  const size_t rowbase = (size_t)(b * 4096 + n * 64) * 1024 + h * 128;
  const bf16* qc = qb + rowbase;
  const bf16* kc = kb + rowbase;
  const bf16* vc = vb + rowbase;
#pragma unroll
  for (int s = 0; s < 4; ++s) {
    int u = tid + s * 256;
    int c = u >> 4, d0 = (u & 15) * 8;
    *(uint4*)&lQ[c * 136 + d0] = *(const uint4*)&qc[(size_t)c * 1024 + d0];
    *(uint4*)&lK[c * 136 + d0] = *(const uint4*)&kc[(size_t)c * 1024 + d0];
    union { uint4 u4; bf16 h8[8]; } vv;
    vv.u4 = *(const uint4*)&vc[(size_t)c * 1024 + d0];
#pragma unroll
    for (int j = 0; j < 8; ++j) lVt[(d0 + j) * 72 + c] = vv.h8[j];
  }
  __syncthreads();
  const int w = tid >> 6, lane = tid & 63, lr = lane & 15, quad = lane >> 4;

  // --- Step 1: P = q @ k^T; wave w computes columns [w*16, w*16+16) ---
  f32x4 p[4] = {};
#pragma unroll
  for (int kk = 0; kk < 4; ++kk) {
    bf16x8 bfrag = *(bf16x8*)&lK[(w * 16 + lr) * 136 + kk * 32 + quad * 8];
#pragma unroll
    for (int i = 0; i < 4; ++i) {
      bf16x8 afrag = *(bf16x8*)&lQ[(i * 16 + lr) * 136 + kk * 32 + quad * 8];
      p[i] = MFMA16(afrag, bfrag, p[i]);
    }
  }
  // mask + decay, write to lP (bf16)
#pragma unroll
  for (int i = 0; i < 4; ++i) {
#pragma unroll
    for (int r = 0; r < 4; ++r) {
      const int row = i * 16 + quad * 4 + r;
      const int col = w * 16 + lr;
      const int diff = row - col;
      const float val =
          (diff >= 0) ? p[i][r] * exp2f((float)diff * log2g) : 0.0f;
      lP[row * 72 + col] = (bf16)val;
    }
  }
  __syncthreads();

  // --- Step 2: o_intra = P @ v; wave w covers dv in [w*32, w*32+32) ---
  f32x4 oacc[4][2] = {};
#pragma unroll
  for (int j = 0; j < 2; ++j) {
    const int dvt = w * 32 + j * 16;
#pragma unroll
    for (int kk = 0; kk < 2; ++kk) {
      bf16x8 bfrag = *(bf16x8*)&lVt[(dvt + lr) * 72 + kk * 32 + quad * 8];
#pragma unroll
      for (int i = 0; i < 4; ++i) {
        bf16x8 afrag = *(bf16x8*)&lP[(i * 16 + lr) * 72 + kk * 32 + quad * 8];
        oacc[i][j] = MFMA16(afrag, bfrag, oacc[i][j]);
      }
    }
  }

  // --- Step 3: o_inter = (q * g^(ci+1)) @ S_prev.  S^T is [dv][dk] bf16 in
  // global; decay folded into A-frag (all 8 elems share row m = i*16+lr). ---
  const bf16* sp = Sp + (size_t)g * 16384;
#pragma unroll
  for (int kk = 0; kk < 4; ++kk) {
    bf16x8 aN[4];
#pragma unroll
    for (int i = 0; i < 4; ++i) {
      bf16x8 a0 = *(bf16x8*)&lQ[(i * 16 + lr) * 136 + kk * 32 + quad * 8];
      const float dq = exp2f((float)(i * 16 + lr + 1) * log2g);
#pragma unroll
      for (int e = 0; e < 8; ++e) a0[e] = (bf16)((float)a0[e] * dq);
      aN[i] = a0;
    }
#pragma unroll
    for (int j = 0; j < 2; ++j) {
      bf16x8 bfrag =
          *(const bf16x8*)&sp[(size_t)(w * 32 + j * 16 + lr) * 128 + kk * 32 + quad * 8];
#pragma unroll
      for (int i = 0; i < 4; ++i) oacc[i][j] = MFMA16(aN[i], bfrag, oacc[i][j]);
    }
  }

  // --- write o chunk ---
  bf16* oc = ob + rowbase;
#pragma unroll
  for (int i = 0; i < 4; ++i)
#pragma unroll
    for (int j = 0; j < 2; ++j)
#pragma unroll
      for (int r = 0; r < 4; ++r) {
        const int row = i * 16 + quad * 4 + r;
        const int col = w * 32 + j * 16 + lr;
        oc[(size_t)row * 1024 + col] = (bf16)oacc[i][j][r];
      }
}

// ---------------------------------------------------------------------------
extern "C" void kernel_launch(void* const* d_in, const int* in_sizes, int n_in,
                              void* d_out, int out_size, void* d_ws,
                              size_t ws_size, hipStream_t stream) {
  const float* X  = (const float*)d_in[0];
  const float* Wq = (const float*)d_in[2];
  const float* Wk = (const float*)d_in[3];
  const float* Wv = (const float*)d_in[4];
  const float* Wo = (const float*)d_in[5];

  char* ws = (char*)d_ws;
  const size_t SZ_QKV = (size_t)8192 * 1024 * sizeof(bf16);  // 16 MiB each
  bf16* qb = (bf16*)(ws);
  bf16* kb = (bf16*)(ws + SZ_QKV);
  bf16* vb = (bf16*)(ws + 2 * SZ_QKV);
  bf16* ob = (bf16*)(ws + 3 * SZ_QKV);
  bf16* Tb = (bf16*)(ws + 4 * SZ_QKV);                       // 32 MiB
  bf16* Wt = (bf16*)(ws + 4 * SZ_QKV + (size_t)16 * 64 * 16384 * sizeof(bf16));

  transpose_w<<<dim3(16, 16, 4), 256, 0, stream>>>(Wq, Wk, Wv, Wo, Wt);

  const float qscale = 0.08838834764831845f;  // 128^-0.5
  gemm_bt<float, bf16><<<dim3(64, 8), 256, 0, stream>>>(X, Wt, qb, qscale);
  gemm_bt<float, bf16><<<dim3(64, 8), 256, 0, stream>>>(X, Wt + (size_t)1 * 1024 * 1024, kb, 1.0f);
  gemm_bt<float, bf16><<<dim3(64, 8), 256, 0, stream>>>(X, Wt + (size_t)2 * 1024 * 1024, vb, 1.0f);

  chunk_kv<<<1024, 256, 0, stream>>>(kb, vb, Tb);
  scan_state<<<1024, 256, 0, stream>>>(Tb);
  chunk_out<<<1024, 256, 0, stream>>>(qb, kb, vb, Tb, ob);

  gemm_bt<bf16, float><<<dim3(64, 8), 256, 0, stream>>>(
      ob, Wt + (size_t)3 * 1024 * 1024, (float*)d_out, 1.0f);
}

// Round 4
// 232.414 us; speedup vs baseline: 1.1152x; 1.1152x over previous
//
#include <hip/hip_runtime.h>
#include <hip/hip_bf16.h>

typedef __bf16 bf16;
typedef __bf16 bf16x8 __attribute__((ext_vector_type(8)));
typedef float f32x4 __attribute__((ext_vector_type(4)));

#define MFMA16(a, b, c) __builtin_amdgcn_mfma_f32_16x16x32_bf16((a), (b), (c), 0, 0, 0)

// Problem: B=2, L=4096, D=1024, H=8, Hd=128, CHUNK=64, NCHUNK=64
// gamma_h = 1 - 2^(-5-h).  Inputs fp32, OUTPUT fp32.

// async 16B global->LDS (gfx950). LDS dest is wave-uniform base + lane*16.
__device__ __forceinline__ void g2l16(const bf16* g, bf16* l) {
  __builtin_amdgcn_global_load_lds(
      (const __attribute__((address_space(1))) void*)g,
      (__attribute__((address_space(3))) void*)l, 16, 0, 0);
}

// ---------------------------------------------------------------------------
// Kernel: fp32 -> bf16 bulk convert (X -> Xb), 8 elems/thread.
// ---------------------------------------------------------------------------
__global__ __launch_bounds__(256) void cvt_bf16(const float* __restrict__ X,
                                                bf16* __restrict__ Y) {
  const size_t i = ((size_t)blockIdx.x * 256 + threadIdx.x) * 8;
  float4 a = *(const float4*)&X[i];
  float4 b = *(const float4*)&X[i + 4];
  union { bf16 h[8]; uint4 u; } p;
  p.h[0] = (bf16)a.x; p.h[1] = (bf16)a.y; p.h[2] = (bf16)a.z; p.h[3] = (bf16)a.w;
  p.h[4] = (bf16)b.x; p.h[5] = (bf16)b.y; p.h[6] = (bf16)b.z; p.h[7] = (bf16)b.w;
  *(uint4*)&Y[i] = p.u;
}

// ---------------------------------------------------------------------------
// Kernel: transpose + fp32->bf16 the four 1024x1024 weights.
// Wt[w][n][k] = (bf16)W[k][n]
// ---------------------------------------------------------------------------
__global__ __launch_bounds__(256) void transpose_w(
    const float* __restrict__ Wq, const float* __restrict__ Wk,
    const float* __restrict__ Wv, const float* __restrict__ Wo,
    bf16* __restrict__ Wt) {
  __shared__ bf16 t[64 * 72];
  const float* src = (blockIdx.z == 0) ? Wq : (blockIdx.z == 1) ? Wk
                     : (blockIdx.z == 2) ? Wv : Wo;
  bf16* dst = Wt + (size_t)blockIdx.z * 1024 * 1024;
  const int k0 = blockIdx.x * 64, n0 = blockIdx.y * 64;
  const int tid = threadIdx.x;
#pragma unroll
  for (int s = 0; s < 4; ++s) {
    int u = tid + s * 256;          // 0..1023
    int r = u >> 4, c4 = (u & 15) * 4;
    float4 f = *(const float4*)&src[(size_t)(k0 + r) * 1024 + n0 + c4];
    t[r * 72 + c4 + 0] = (bf16)f.x;
    t[r * 72 + c4 + 1] = (bf16)f.y;
    t[r * 72 + c4 + 2] = (bf16)f.z;
    t[r * 72 + c4 + 3] = (bf16)f.w;
  }
  __syncthreads();
#pragma unroll
  for (int s = 0; s < 2; ++s) {
    int u = tid + s * 256;
    int r = u >> 3, cc = u & 7;     // output row n0+r, k-chunk cc
    union { bf16 h[8]; uint4 u4; } pk;
#pragma unroll
    for (int j = 0; j < 8; ++j) pk.h[j] = t[(cc * 8 + j) * 72 + r];
    *(uint4*)&dst[(size_t)(n0 + r) * 1024 + k0 + cc * 8] = pk.u4;
  }
}

// ---------------------------------------------------------------------------
// GEMM: C = alpha * (A @ Bt^T).  A: M x 1024 bf16 row-major,
// Bt: 1024 x 1024 bf16 = B^T row-major, C: M x 1024 (TC = bf16 or fp32).
// 128x128 tile, BK=64, 4 waves. global_load_lds(16B) staging with XOR-swizzle:
// logical 16B-chunk c of row r lives at physical chunk c^(r&7) (unpadded rows,
// stride 64 bf16) -> fragment ds_read_b128 spreads across all 32 banks 2-way.
// If QKV!=0: gridDim.z selects Wt slice z and output slice z (q gets alpha).
// ---------------------------------------------------------------------------
template <typename TC, int QKV>
__global__ __launch_bounds__(256) void gemm_lds(
    const bf16* __restrict__ A, const bf16* __restrict__ Bt,
    TC* __restrict__ C, float alpha) {
  __shared__ bf16 lA[128 * 64];
  __shared__ bf16 lB[128 * 64];
  const int m0 = blockIdx.x * 128, n0 = blockIdx.y * 128;
  if (QKV) {
    Bt += (size_t)blockIdx.z * 1024 * 1024;
    C += (size_t)blockIdx.z * 8192 * 1024;
    if (blockIdx.z != 0) alpha = 1.0f;
  }
  const int tid = threadIdx.x;
  const int w = tid >> 6, lane = tid & 63, lr = lane & 15, quad = lane >> 4;
  const int wm = w >> 1, wn = w & 1;

  // staging map: wave w stages rows [w*32, w*32+32) in 4 issues of 8 rows.
  const int srow = w * 32 + (lane >> 3);              // row for issue 0
  const int clog = (lane & 7) ^ ((lane >> 3) & 7);    // swizzled 16B chunk
  const bf16* gA = A + (size_t)(m0 + srow) * 1024 + clog * 8;
  const bf16* gB = Bt + (size_t)(n0 + srow) * 1024 + clog * 8;

  f32x4 acc[4][4] = {};

  for (int it = 0; it < 16; ++it) {
    const int k0 = it * 64;
#pragma unroll
    for (int is = 0; is < 4; ++is) {
      g2l16(gA + (size_t)is * 8 * 1024 + k0, &lA[(w * 32 + is * 8) * 64]);
      g2l16(gB + (size_t)is * 8 * 1024 + k0, &lB[(w * 32 + is * 8) * 64]);
    }
    __syncthreads();
#pragma unroll
    for (int kk = 0; kk < 2; ++kk) {
      bf16x8 af[4], bfv[4];
#pragma unroll
      for (int i = 0; i < 4; ++i) {
        const int m = wm * 64 + i * 16 + lr;
        af[i] = *(bf16x8*)&lA[m * 64 + (((kk * 4 + quad) ^ (lr & 7)) * 8)];
      }
#pragma unroll
      for (int j = 0; j < 4; ++j) {
        const int n = wn * 64 + j * 16 + lr;
        bfv[j] = *(bf16x8*)&lB[n * 64 + (((kk * 4 + quad) ^ (lr & 7)) * 8)];
      }
#pragma unroll
      for (int i = 0; i < 4; ++i)
#pragma unroll
        for (int j = 0; j < 4; ++j)
          acc[i][j] = MFMA16(af[i], bfv[j], acc[i][j]);
    }
    __syncthreads();
  }
  // Epilogue: D layout col=lane&15, row=quad*4+r
#pragma unroll
  for (int i = 0; i < 4; ++i) {
#pragma unroll
    for (int j = 0; j < 4; ++j) {
      const int row = m0 + wm * 64 + i * 16 + quad * 4;
      const int col = n0 + wn * 64 + j * 16 + lr;
#pragma unroll
      for (int r = 0; r < 4; ++r)
        C[(size_t)(row + r) * 1024 + col] = (TC)(acc[i][j][r] * alpha);
    }
  }
}

// ---------------------------------------------------------------------------
// Phase A: per-(b,h,chunk) T^T[dv][dk] = sum_c k[c][dk]*g^(63-c)*v[c][dv]
// grid = 1024 (bh*64+n), bf16 output at Tb + g*16384, layout [dv][dk].
// ---------------------------------------------------------------------------
__global__ __launch_bounds__(256) void chunk_kv(
    const bf16* __restrict__ kb, const bf16* __restrict__ vb,
    bf16* __restrict__ Tb) {
  __shared__ bf16 lK[128 * 72];  // [dk][c] with decay folded in
  __shared__ bf16 lV[128 * 72];  // [dv][c]
  const int g = blockIdx.x;
  const int bh = g >> 6, n = g & 63, b = bh >> 3, h = bh & 7;
  const float log2g = log2f(1.0f - exp2f(-5.0f - (float)h));
  const int tid = threadIdx.x;
  const size_t rowbase = (size_t)(b * 4096 + n * 64) * 1024 + h * 128;
  const bf16* kc = kb + rowbase;
  const bf16* vc = vb + rowbase;
#pragma unroll
  for (int s = 0; s < 4; ++s) {
    int u = tid + s * 256;
    int c = u >> 4, d0 = (u & 15) * 8;
    union { uint4 u4; bf16 h8[8]; } kv, vv;
    kv.u4 = *(const uint4*)&kc[(size_t)c * 1024 + d0];
    vv.u4 = *(const uint4*)&vc[(size_t)c * 1024 + d0];
    const float dec = exp2f((float)(63 - c) * log2g);
#pragma unroll
    for (int j = 0; j < 8; ++j) {
      lK[(d0 + j) * 72 + c] = (bf16)((float)kv.h8[j] * dec);
      lV[(d0 + j) * 72 + c] = vv.h8[j];
    }
  }
  __syncthreads();
  const int w = tid >> 6, lane = tid & 63, lr = lane & 15, quad = lane >> 4;
  const int wm = w >> 1, wn = w & 1;
  f32x4 acc[4][4] = {};
#pragma unroll
  for (int kk = 0; kk < 2; ++kk) {
    bf16x8 af[4], bv[4];
#pragma unroll
    for (int i = 0; i < 4; ++i)
      af[i] = *(bf16x8*)&lK[(wm * 64 + i * 16 + lr) * 72 + kk * 32 + quad * 8];
#pragma unroll
    for (int j = 0; j < 4; ++j)
      bv[j] = *(bf16x8*)&lV[(wn * 64 + j * 16 + lr) * 72 + kk * 32 + quad * 8];
#pragma unroll
    for (int i = 0; i < 4; ++i)
#pragma unroll
      for (int j = 0; j < 4; ++j)
        acc[i][j] = MFMA16(af[i], bv[j], acc[i][j]);
  }
  bf16* tchunk = Tb + (size_t)g * 16384;
#pragma unroll
  for (int i = 0; i < 4; ++i) {
#pragma unroll
    for (int j = 0; j < 4; ++j) {
      const int dk = wm * 64 + i * 16 + quad * 4;  // row of T (r advances dk)
      const int dv = wn * 64 + j * 16 + lr;        // col of T
      union { bf16 h4[4]; uint2 u2; } pk;
#pragma unroll
      for (int r = 0; r < 4; ++r) pk.h4[r] = (bf16)acc[i][j][r];
      *(uint2*)&tchunk[(size_t)dv * 128 + dk] = pk.u2;  // transposed store
    }
  }
}

// ---------------------------------------------------------------------------
// Phase B: in-place exclusive prefix scan over chunks:
// slot n <- S_{n-1};  S <- gamma^64 * S + T_n.  fp32 accumulator in register.
// ---------------------------------------------------------------------------
__global__ __launch_bounds__(256) void scan_state(bf16* __restrict__ Tb) {
  const int blk = blockIdx.x;
  const int bh = blk >> 6, seg = blk & 63, h = bh & 7;
  const float gs = exp2f(64.0f * log2f(1.0f - exp2f(-5.0f - (float)h)));
  const size_t base = (size_t)bh * 64 * 16384 + (size_t)seg * 256 + threadIdx.x;
  float S = 0.0f;
#pragma unroll 8
  for (int n = 0; n < 64; ++n) {
    const size_t a = base + (size_t)n * 16384;
    const float t = (float)Tb[a];
    Tb[a] = (bf16)S;
    S = gs * S + t;
  }
}

// ---------------------------------------------------------------------------
// Phase C: per-(b,h,chunk) output:
// P = (q@k^T) * D(mask/decay);  o = P@v + (q * g^(i+1)) @ S_prev
// ---------------------------------------------------------------------------
__global__ __launch_bounds__(256) void chunk_out(
    const bf16* __restrict__ qb, const bf16* __restrict__ kb,
    const bf16* __restrict__ vb, const bf16* __restrict__ Sp,
    bf16* __restrict__ ob) {
  __shared__ bf16 lQ[64 * 136];   // [c][dk]
  __shared__ bf16 lK[64 * 136];   // [c][dk]
  __shared__ bf16 lVt[128 * 72];  // [dv][c]
  __shared__ bf16 lP[64 * 72];    // [ci][cj] masked scores
  const int g = blockIdx.x;
  const int bh = g >> 6, n = g & 63, b = bh >> 3, h = bh & 7;
  const float log2g = log2f(1.0f - exp2f(-5.0f - (float)h));
  const int tid = threadIdx.x;
  const size_t rowbase = (size_t)(b * 4096 + n * 64) * 1024 + h * 128;
  const bf16* qc = qb + rowbase;
  const bf16* kc = kb + rowbase;
  const bf16* vc = vb + rowbase;
#pragma unroll
  for (int s = 0; s < 4; ++s) {
    int u = tid + s * 256;
    int c = u >> 4, d0 = (u & 15) * 8;
    *(uint4*)&lQ[c * 136 + d0] = *(const uint4*)&qc[(size_t)c * 1024 + d0];
    *(uint4*)&lK[c * 136 + d0] = *(const uint4*)&kc[(size_t)c * 1024 + d0];
    union { uint4 u4; bf16 h8[8]; } vv;
    vv.u4 = *(const uint4*)&vc[(size_t)c * 1024 + d0];
#pragma unroll
    for (int j = 0; j < 8; ++j) lVt[(d0 + j) * 72 + c] = vv.h8[j];
  }
  __syncthreads();
  const int w = tid >> 6, lane = tid & 63, lr = lane & 15, quad = lane >> 4;

  // --- Step 1: P = q @ k^T; wave w computes columns [w*16, w*16+16) ---
  f32x4 p[4] = {};
#pragma unroll
  for (int kk = 0; kk < 4; ++kk) {
    bf16x8 bfrag = *(bf16x8*)&lK[(w * 16 + lr) * 136 + kk * 32 + quad * 8];
#pragma unroll
    for (int i = 0; i < 4; ++i) {
      bf16x8 afrag = *(bf16x8*)&lQ[(i * 16 + lr) * 136 + kk * 32 + quad * 8];
      p[i] = MFMA16(afrag, bfrag, p[i]);
    }
  }
  // mask + decay, write to lP (bf16)
#pragma unroll
  for (int i = 0; i < 4; ++i) {
#pragma unroll
    for (int r = 0; r < 4; ++r) {
      const int row = i * 16 + quad * 4 + r;
      const int col = w * 16 + lr;
      const int diff = row - col;
      const float val =
          (diff >= 0) ? p[i][r] * exp2f((float)diff * log2g) : 0.0f;
      lP[row * 72 + col] = (bf16)val;
    }
  }
  __syncthreads();

  // --- Step 2: o_intra = P @ v; wave w covers dv in [w*32, w*32+32) ---
  f32x4 oacc[4][2] = {};
#pragma unroll
  for (int j = 0; j < 2; ++j) {
    const int dvt = w * 32 + j * 16;
#pragma unroll
    for (int kk = 0; kk < 2; ++kk) {
      bf16x8 bfrag = *(bf16x8*)&lVt[(dvt + lr) * 72 + kk * 32 + quad * 8];
#pragma unroll
      for (int i = 0; i < 4; ++i) {
        bf16x8 afrag = *(bf16x8*)&lP[(i * 16 + lr) * 72 + kk * 32 + quad * 8];
        oacc[i][j] = MFMA16(afrag, bfrag, oacc[i][j]);
      }
    }
  }

  // --- Step 3: o_inter = (q * g^(ci+1)) @ S_prev.  S^T is [dv][dk] bf16 in
  // global; decay folded into A-frag (all 8 elems share row m = i*16+lr). ---
  const bf16* sp = Sp + (size_t)g * 16384;
#pragma unroll
  for (int kk = 0; kk < 4; ++kk) {
    bf16x8 aN[4];
#pragma unroll
    for (int i = 0; i < 4; ++i) {
      bf16x8 a0 = *(bf16x8*)&lQ[(i * 16 + lr) * 136 + kk * 32 + quad * 8];
      const float dq = exp2f((float)(i * 16 + lr + 1) * log2g);
#pragma unroll
      for (int e = 0; e < 8; ++e) a0[e] = (bf16)((float)a0[e] * dq);
      aN[i] = a0;
    }
#pragma unroll
    for (int j = 0; j < 2; ++j) {
      bf16x8 bfrag =
          *(const bf16x8*)&sp[(size_t)(w * 32 + j * 16 + lr) * 128 + kk * 32 + quad * 8];
#pragma unroll
      for (int i = 0; i < 4; ++i) oacc[i][j] = MFMA16(aN[i], bfrag, oacc[i][j]);
    }
  }

  // --- write o chunk ---
  bf16* oc = ob + rowbase;
#pragma unroll
  for (int i = 0; i < 4; ++i)
#pragma unroll
    for (int j = 0; j < 2; ++j)
#pragma unroll
      for (int r = 0; r < 4; ++r) {
        const int row = i * 16 + quad * 4 + r;
        const int col = w * 32 + j * 16 + lr;
        oc[(size_t)row * 1024 + col] = (bf16)oacc[i][j][r];
      }
}

// ---------------------------------------------------------------------------
extern "C" void kernel_launch(void* const* d_in, const int* in_sizes, int n_in,
                              void* d_out, int out_size, void* d_ws,
                              size_t ws_size, hipStream_t stream) {
  const float* X  = (const float*)d_in[0];
  const float* Wq = (const float*)d_in[2];
  const float* Wk = (const float*)d_in[3];
  const float* Wv = (const float*)d_in[4];
  const float* Wo = (const float*)d_in[5];

  char* ws = (char*)d_ws;
  const size_t SZ_QKV = (size_t)8192 * 1024 * sizeof(bf16);  // 16 MiB each
  bf16* qb = (bf16*)(ws);                                    // q,k,v contiguous
  bf16* ob = (bf16*)(ws + 3 * SZ_QKV);
  bf16* Tb = (bf16*)(ws + 4 * SZ_QKV);                       // 32 MiB
  bf16* Wt = (bf16*)(ws + 6 * SZ_QKV);                       // 8 MiB
  bf16* Xb = (bf16*)(ws + 6 * SZ_QKV + (size_t)4 * 1024 * 1024 * sizeof(bf16));
  bf16* kb = qb + (size_t)8192 * 1024;
  bf16* vb = kb + (size_t)8192 * 1024;

  cvt_bf16<<<4096, 256, 0, stream>>>(X, Xb);
  transpose_w<<<dim3(16, 16, 4), 256, 0, stream>>>(Wq, Wk, Wv, Wo, Wt);

  const float qscale = 0.08838834764831845f;  // 128^-0.5
  // fused q/k/v projection: z selects weight + output slice
  gemm_lds<bf16, 1><<<dim3(64, 8, 3), 256, 0, stream>>>(Xb, Wt, qb, qscale);

  chunk_kv<<<1024, 256, 0, stream>>>(kb, vb, Tb);
  scan_state<<<1024, 256, 0, stream>>>(Tb);
  chunk_out<<<1024, 256, 0, stream>>>(qb, kb, vb, Tb, ob);

  gemm_lds<float, 0><<<dim3(64, 8), 256, 0, stream>>>(
      ob, Wt + (size_t)3 * 1024 * 1024, (float*)d_out, 1.0f);
}